// Round 1
// baseline (255.609 us; speedup 1.0000x reference)
//
#include <hip/hip_runtime.h>
#include <math.h>
#include <stdint.h>

// Problem constants (fixed by the reference)
#define NB   32768
#define DIN  512
#define NH1  128
#define NH2  64
#define NMC  10

// ---------------------------------------------------------------------------
// Threefry-2x32, exactly matching jax/_src/prng.py (20 rounds).
// ---------------------------------------------------------------------------
__host__ __device__ __forceinline__ uint32_t rotl32(uint32_t x, uint32_t r) {
  return (x << r) | (x >> (32u - r));
}

__host__ __device__ __forceinline__ void tf2x32(uint32_t k0, uint32_t k1,
                                                uint32_t x0, uint32_t x1,
                                                uint32_t& o0, uint32_t& o1) {
  const uint32_t ks2 = k0 ^ k1 ^ 0x1BD11BDAu;
  x0 += k0; x1 += k1;
#define TF_RND(r) { x0 += x1; x1 = rotl32(x1, r); x1 ^= x0; }
  TF_RND(13u) TF_RND(15u) TF_RND(26u) TF_RND(6u)
  x0 += k1;  x1 += ks2 + 1u;
  TF_RND(17u) TF_RND(29u) TF_RND(16u) TF_RND(24u)
  x0 += ks2; x1 += k0 + 2u;
  TF_RND(13u) TF_RND(15u) TF_RND(26u) TF_RND(6u)
  x0 += k0;  x1 += k1 + 3u;
  TF_RND(17u) TF_RND(29u) TF_RND(16u) TF_RND(24u)
  x0 += k1;  x1 += ks2 + 4u;
  TF_RND(13u) TF_RND(15u) TF_RND(26u) TF_RND(6u)
  x0 += ks2; x1 += k0 + 5u;
#undef TF_RND
  o0 = x0; o1 = x1;
}

// Partitionable random_bits for a 32-bit draw at flat index idx (hi word = 0
// since all our sizes < 2^32): bits = o0 ^ o1 of threefry(key, (0, idx)).
__device__ __forceinline__ uint32_t rb_part(uint32_t k0, uint32_t k1, uint32_t idx) {
  uint32_t a, b;
  tf2x32(k0, k1, 0u, idx, a, b);
  return a ^ b;
}

__device__ __forceinline__ float bits_to_uniform(uint32_t bits) {
  return __uint_as_float((bits >> 9) | 0x3f800000u) - 1.0f;
}

// ---------------------------------------------------------------------------
// Kernel 1: h = relu(x @ W1 + b1) * mask_s  (written to ws), plus fused
// a_mean = h@Wam + bam and a_var = exp(h@Wav + bav) epilogue.
// Block: 256 threads, tile 64 rows x 128 cols (full H1), BK=32.
// ---------------------------------------------------------------------------
__global__ __launch_bounds__(256) void k1_gemm_h(
    const float* __restrict__ x, const float* __restrict__ W1,
    const float* __restrict__ b1, const float* __restrict__ Wam,
    const float* __restrict__ bam, const float* __restrict__ Wav,
    const float* __restrict__ bav,
    float* __restrict__ hout, float* __restrict__ out,
    uint32_t s0, uint32_t s1)
{
  __shared__ float xs[32][68];     // [kk][row], padded (bank-friendly)
  __shared__ float w1s[32][132];   // [kk][col], padded, 16B-aligned rows
  __shared__ float hs[64][128];    // h tile for the a_mean/a_var epilogue

  const int tid = threadIdx.x;
  const int b0  = blockIdx.x * 64;
  const int tr  = tid >> 4;        // 0..15 -> 4 rows each
  const int tc  = tid & 15;        // 0..15 -> 8 cols each

  float acc[4][8];
#pragma unroll
  for (int i = 0; i < 4; ++i)
#pragma unroll
    for (int j = 0; j < 8; ++j) acc[i][j] = 0.0f;

  for (int kt = 0; kt < DIN; kt += 32) {
    // stage x tile (64x32) transposed into xs
    {
      const int rr = tid >> 3;     // 0..31
      const int cg = tid & 7;      // 0..7 (x4 cols)
#pragma unroll
      for (int l = 0; l < 2; ++l) {
        float4 v = *(const float4*)(x + (size_t)(b0 + rr + 32 * l) * DIN + kt + cg * 4);
        xs[cg * 4 + 0][rr + 32 * l] = v.x;
        xs[cg * 4 + 1][rr + 32 * l] = v.y;
        xs[cg * 4 + 2][rr + 32 * l] = v.z;
        xs[cg * 4 + 3][rr + 32 * l] = v.w;
      }
      // stage W1 tile (32x128)
#pragma unroll
      for (int l = 0; l < 4; ++l) {
        int idx = tid + l * 256;   // 0..1023
        int r2  = idx >> 5;        // 0..31
        int c4  = (idx & 31) * 4;  // 0..124
        *(float4*)&w1s[r2][c4] = *(const float4*)(W1 + (size_t)(kt + r2) * NH1 + c4);
      }
    }
    __syncthreads();
#pragma unroll 8
    for (int kk = 0; kk < 32; ++kk) {
      float a[4], bb[8];
      *(float4*)a        = *(const float4*)&xs[kk][tr * 4];
      *(float4*)&bb[0]   = *(const float4*)&w1s[kk][tc * 8];
      *(float4*)&bb[4]   = *(const float4*)&w1s[kk][tc * 8 + 4];
#pragma unroll
      for (int i = 0; i < 4; ++i)
#pragma unroll
        for (int j = 0; j < 8; ++j)
          acc[i][j] = fmaf(a[i], bb[j], acc[i][j]);
    }
    __syncthreads();
  }

  // Epilogue A: bias, relu, shared dropout (threefry per element), store h.
  const float inv_s = 1.0f / 0.9f;   // same IEEE division as reference mask/KEEP
  float hv[4][8];
#pragma unroll
  for (int i = 0; i < 4; ++i) {
    const int row = b0 + tr * 4 + i;
#pragma unroll
    for (int j = 0; j < 8; ++j) {
      const int col = tc * 8 + j;
      float v = acc[i][j] + b1[col];
      v = fmaxf(v, 0.0f);
      uint32_t bits = rb_part(s0, s1, (uint32_t)(row * NH1 + col));
      float u = bits_to_uniform(bits);
      hv[i][j] = (u < 0.9f) ? v * inv_s : 0.0f;
    }
  }
#pragma unroll
  for (int i = 0; i < 4; ++i) {
    const int row = b0 + tr * 4 + i;
    *(float4*)&hs[tr * 4 + i][tc * 8]     = *(float4*)&hv[i][0];
    *(float4*)&hs[tr * 4 + i][tc * 8 + 4] = *(float4*)&hv[i][4];
    *(float4*)(hout + (size_t)row * NH1 + tc * 8)     = *(float4*)&hv[i][0];
    *(float4*)(hout + (size_t)row * NH1 + tc * 8 + 4) = *(float4*)&hv[i][4];
  }
  __syncthreads();

  // Epilogue B: a_mean / a_var. Thread (f, g) handles 16 rows (r*4+g).
  const int f = tid & 63;
  const int g = tid >> 6;            // 0..3
  float am[16], av[16];
#pragma unroll
  for (int r = 0; r < 16; ++r) { am[r] = 0.0f; av[r] = 0.0f; }
#pragma unroll 4
  for (int k = 0; k < NH1; ++k) {
    const float wa = Wam[k * NH2 + f];
    const float wv = Wav[k * NH2 + f];
#pragma unroll
    for (int r = 0; r < 16; ++r) {
      const float h = hs[r * 4 + g][k];   // wave-uniform address: broadcast
      am[r] = fmaf(h, wa, am[r]);
      av[r] = fmaf(h, wv, av[r]);
    }
  }
  const float bamf = bam[f], bavf = bav[f];
#pragma unroll
  for (int r = 0; r < 16; ++r) {
    const int row = b0 + r * 4 + g;
    out[(size_t)row * NH2 + f]                       = am[r] + bamf;
    out[(size_t)NB * NH2 + (size_t)row * NH2 + f]    = expf(av[r] + bavf);
  }
}

// ---------------------------------------------------------------------------
// Kernel 2: MC-dropout heads. Block = 256 threads = 4 rows x 64 features.
// Per row, the 10 masked h values per k are materialized once in LDS and
// broadcast to all 64 f-lanes; e_mean/e_var computed from 10 registers.
// ---------------------------------------------------------------------------
__global__ __launch_bounds__(256) void k2_mc(
    const float* __restrict__ hin, const float* __restrict__ We,
    const float* __restrict__ be, float* __restrict__ out,
    uint32_t m0, uint32_t m1, float p_mc, float inv_mc)
{
  __shared__ float wes[NH1][NH2 + 1];   // +1 pad: (k+f)%32 banks, conflict-free
  __shared__ float hs2[4][NH1];
  __shared__ float hms[4][NH1][12];     // 10 masked values + pad to 48B stride

  const int tid = threadIdx.x;
  const int b0  = blockIdx.x * 4;

  for (int idx = tid; idx < NH1 * NH2; idx += 256)
    wes[idx >> 6][idx & 63] = We[idx];
#pragma unroll
  for (int l = 0; l < 2; ++l) {
    const int idx = tid + l * 256;
    hs2[idx >> 7][idx & 127] = hin[(size_t)(b0 + (idx >> 7)) * NH1 + (idx & 127)];
  }
  __syncthreads();

  // Generate the 10 MC masks for 2 (row,k) elements per thread.
#pragma unroll
  for (int l = 0; l < 2; ++l) {
    const int e  = tid + l * 256;
    const int r2 = e >> 7;
    const int k  = e & 127;
    const uint32_t base = (uint32_t)((b0 + r2) * NH1 + k);
    const float hvmul = hs2[r2][k] * inv_mc;
#pragma unroll
    for (int mm = 0; mm < NMC; ++mm) {
      uint32_t bits = rb_part(m0, m1, base + (uint32_t)mm * (uint32_t)(NB * NH1));
      float u = bits_to_uniform(bits);
      hms[r2][k][mm] = (u < p_mc) ? hvmul : 0.0f;
    }
  }
  __syncthreads();

  const int f = tid & 63;
  const int r = tid >> 6;
  float o[NMC];
#pragma unroll
  for (int m = 0; m < NMC; ++m) o[m] = 0.0f;

#pragma unroll 2
  for (int k = 0; k < NH1; ++k) {
    const float w = wes[k][f];
    const float* hp = &hms[r][k][0];      // 48B-aligned
    float4 h0 = *(const float4*)hp;
    float4 h1 = *(const float4*)(hp + 4);
    float2 h2 = *(const float2*)(hp + 8);
    o[0] = fmaf(h0.x, w, o[0]);  o[1] = fmaf(h0.y, w, o[1]);
    o[2] = fmaf(h0.z, w, o[2]);  o[3] = fmaf(h0.w, w, o[3]);
    o[4] = fmaf(h1.x, w, o[4]);  o[5] = fmaf(h1.y, w, o[5]);
    o[6] = fmaf(h1.z, w, o[6]);  o[7] = fmaf(h1.w, w, o[7]);
    o[8] = fmaf(h2.x, w, o[8]);  o[9] = fmaf(h2.y, w, o[9]);
  }

  const float bef = be[f];
  float s = 0.0f;
#pragma unroll
  for (int m = 0; m < NMC; ++m) { o[m] += bef; s += o[m]; }
  const float mean = s / 10.0f;
  float var = 0.0f;
#pragma unroll
  for (int m = 0; m < NMC; ++m) { const float d = o[m] - mean; var = fmaf(d, d, var); }
  var /= 9.0f;

  const int row = b0 + r;
  out[(size_t)2 * NB * NH2 + (size_t)row * NH2 + f] = mean;
  out[(size_t)3 * NB * NH2 + (size_t)row * NH2 + f] = var;
}

// ---------------------------------------------------------------------------
extern "C" void kernel_launch(void* const* d_in, const int* in_sizes, int n_in,
                              void* d_out, int out_size, void* d_ws, size_t ws_size,
                              hipStream_t stream) {
  const float* x   = (const float*)d_in[0];
  const float* W1  = (const float*)d_in[1];
  const float* b1  = (const float*)d_in[2];
  const float* Wam = (const float*)d_in[3];
  const float* bam = (const float*)d_in[4];
  const float* Wav = (const float*)d_in[5];
  const float* bav = (const float*)d_in[6];
  const float* We  = (const float*)d_in[7];
  const float* be  = (const float*)d_in[8];
  float* out = (float*)d_out;
  float* hws = (float*)d_ws;   // h: 32768 x 128 f32 = 16 MB

  // jax.random.key(42) -> (0, 42); partitionable (fold-like) split:
  // k_shared = threefry(key, (0,0)); k_mc = threefry(key, (0,1)).
  uint32_t s0, s1, m0, m1;
  tf2x32(0u, 42u, 0u, 0u, s0, s1);
  tf2x32(0u, 42u, 0u, 1u, m0, m1);

  const float p_mc  = (float)pow(0.9, 10.0);  // f32(0.9**10), matches jax cast
  const float inv_mc = 1.0f / p_mc;           // same division as mask/keep_eff

  k1_gemm_h<<<dim3(NB / 64), dim3(256), 0, stream>>>(
      x, W1, b1, Wam, bam, Wav, bav, hws, out, s0, s1);
  k2_mc<<<dim3(NB / 4), dim3(256), 0, stream>>>(
      hws, We, be, out, m0, m1, p_mc, inv_mc);
}